// Round 15
// baseline (286.496 us; speedup 1.0000x reference)
//
#include <hip/hip_runtime.h>

// AdultConnectomeNetwork: 3 layers of xt = A_sp @ (W_sp @ xt) + bias.
// Round 30: revert to r26 (best measured, 233.0us) + pass2 work deletion.
// r27/r28/r29 (de-stage, windows, cursor padding) were all neutral-to-worse;
// five pass1 variants pinned at 45-50us => stop attacking it (unidentified
// serial resource). Evidence-backed levers only:
//  1. pass1 also emits per-row counts (1.6M global atomics on 200KB
//     L2-resident rowcnt; r22's hist2 proved the pattern cheap).
//  2. pass2 DROPS its histogram loop: reads rowcnt for its 128 rows, keeps
//     the LDS scan, reads the e1 window ONCE (was twice) -> deletes ~19MB
//     of reads + 1.6M LDS atomics from the serial chain (deletion lever:
//     r19 -5us, r25 -6us).
//  3. Transpose blocks scheduled FIRST (r28; order-only, overlaps sort).
//  - Otherwise bit-identical r26: staged pass1 (CHUNK=3072, 391 bins,
//    vectorized int4/float4 edge loads, wave-shuffle scan, cursor-claimed
//    bin windows, interleaved uint2 e1), r20 spmm, scaled fp16 state,
//    fused coalesced transposes.
// Hardening: computed indices clamped (logic error -> absmax fail, not fault).

#define NN 50000
#define NNZ_E 1600000
#define NB (NN * 32)
#define CHUNK 3072
#define NBLK1 ((NNZ_E + CHUNK - 1) / CHUNK)      // 521
#define NBIN ((NN + 127) / 128)                  // 391 bins of 128 rows
#define NNP 50048                                // NN padded (rowcnt array)
#define CAP2 5120                                // bin fill cap (mean 4092, +16 sigma)
#define BCAP1 6144                               // e1 window slots per bin
#define LENE (NBIN * BCAP1)                      // 2402304 e1 slots (19.2 MB)
#define BCAP 6144                                // padded kv capacity per bin
#define LENP (NBIN * BCAP)                       // 2402304 padded kv slots
#define TIN_BLKS 196                             // transpose tiles of 256 n (FIRST)

__device__ __forceinline__ int clampi(int v, int hi) {  // [0, hi]
    v = v < 0 ? 0 : v;
    return v > hi ? hi : v;
}

__device__ __forceinline__ unsigned short f2h(float v) {
    union { _Float16 h; unsigned short u; } cv;
    cv.h = (_Float16)v;
    return cv.u;
}

__device__ __forceinline__ float kv_val(unsigned kv) {
    union { unsigned short u; _Float16 h; } cv;
    cv.u = (unsigned short)(kv >> 16);
    return (float)cv.h;
}

// Pass 1 (staged, r26 form): blocks < TIN_BLKS run the LDS-tiled coalesced
// input transpose (scheduled FIRST); remaining 521 blocks: vectorized edge
// loads -> LDS bin hist (+ global per-row counts) -> wave-shuffle scan ->
// cursor-claim of bin window segments -> LDS staging -> dense burst writes
// of interleaved uint2 {key, aw}. key = (row<<16)|col.
__global__ __launch_bounds__(256) void pass1_kernel(
        const int* __restrict__ row, const int* __restrict__ col,
        const float* __restrict__ a, const float* __restrict__ w,
        int* __restrict__ cursor, int* __restrict__ rowcnt,
        uint2* __restrict__ e1,
        const float* __restrict__ x, _Float16* __restrict__ xt) {
    __shared__ int h[NBIN];                  // counts -> staging cursors
    __shared__ int hscan[NBIN];              // block-local exclusive scan
    __shared__ int hoff[NBIN];               // claimed e1 index per bin
    __shared__ int wsum[4];
    __shared__ unsigned sBuf[2 * CHUNK];     // 24 KB: sKey | sAW, or transpose tile
    int blk = blockIdx.x, tid = threadIdx.x;

    if (blk < TIN_BLKS) {                    // ---- fused coalesced transpose ----
        _Float16* tl = (_Float16*)sBuf;      // [256][33] fp16 tile (16.9 KB)
        int n0 = blk * 256;
        int n = n0 + tid;
#pragma unroll 8
        for (int b = 0; b < 32; ++b) {       // coalesced x reads (1KB/wave rows)
            float v = (n < NN) ? x[b * NN + n] : 0.0f;
            tl[tid * 33 + b] = (_Float16)v;
        }
        __syncthreads();
#pragma unroll
        for (int k = 0; k < 4; ++k) {        // coalesced uint4 stores (16B/lane)
            int o = (tid + 256 * k) * 8;     // output offset within tile
            int nl = o >> 5;
            int b0 = o & 31;
            int nn = n0 + nl;
            if (nn < NN) {
                union { uint4 u4; _Float16 hh[8]; } pk;
#pragma unroll
                for (int j = 0; j < 8; ++j) pk.hh[j] = tl[nl * 33 + b0 + j];
                *(uint4*)&xt[nn * 32 + b0] = pk.u4;
            }
        }
        return;
    }

    int base = (blk - TIN_BLKS) * CHUNK;
    int n = NNZ_E - base; if (n > CHUNK) n = CHUNK;   // 3072 or 2560 (both %4==0)
    int nv = n >> 2;
    unsigned* sKey = sBuf;
    unsigned* sAW  = sBuf + CHUNK;

    for (int j = tid; j < NBIN; j += 256) h[j] = 0;
    __syncthreads();

    // vectorized edge loads; edges stay in registers through staging
    int rr[12], cc[12];
    unsigned aw2[12];
    int ne = 0;
    const int4*   rv4 = (const int4*)row;
    const int4*   cv4 = (const int4*)col;
    const float4* av4 = (const float4*)a;
    const float4* wv4 = (const float4*)w;
    int b4 = base >> 2;
    for (int t4 = tid; t4 < nv; t4 += 256) {
        int4 r = rv4[b4 + t4];
        int4 c = cv4[b4 + t4];
        float4 af = av4[b4 + t4];
        float4 wf = wv4[b4 + t4];
        rr[ne] = r.x; cc[ne] = c.x; aw2[ne] = ((unsigned)f2h(af.x) << 16) | f2h(wf.x); ++ne;
        rr[ne] = r.y; cc[ne] = c.y; aw2[ne] = ((unsigned)f2h(af.y) << 16) | f2h(wf.y); ++ne;
        rr[ne] = r.z; cc[ne] = c.z; aw2[ne] = ((unsigned)f2h(af.z) << 16) | f2h(wf.z); ++ne;
        rr[ne] = r.w; cc[ne] = c.w; aw2[ne] = ((unsigned)f2h(af.w) << 16) | f2h(wf.w); ++ne;
    }
    // LDS bin histogram + global per-row counts (feeds pass2's scan)
    for (int i = 0; i < ne; ++i) {
        int r = clampi(rr[i], NN - 1);
        atomicAdd(&h[r >> 7], 1);
        atomicAdd(&rowcnt[r], 1);            // fire-and-forget, L2-resident
    }
    __syncthreads();

    // exclusive prefix over per-thread (c0+c1) via wave shuffle (2 barriers)
    int j0 = tid * 2, j1 = tid * 2 + 1;
    int c0 = (j0 < NBIN) ? h[j0] : 0;
    int c1 = (j1 < NBIN) ? h[j1] : 0;
    int tsum = c0 + c1;
    int lane = tid & 63, wid = tid >> 6;
    int inc = tsum;
#pragma unroll
    for (int off = 1; off < 64; off <<= 1) {
        int u = __shfl_up(inc, off, 64);
        if (lane >= off) inc += u;
    }
    if (lane == 63) wsum[wid] = inc;
    __syncthreads();                         // also orders h[] reads vs writes below
    int wo = 0;
#pragma unroll
    for (int q = 0; q < 4; ++q) if (q < wid) wo += wsum[q];
    int ex = wo + inc - tsum;

    // claim global window segments (one atomic per nonempty bin)
    if (j0 < NBIN) {
        hscan[j0] = ex;
        h[j0] = ex;
        int b0 = c0 ? atomicAdd(&cursor[j0], c0) : 0;
        hoff[j0] = j0 * BCAP1 + clampi(b0, BCAP1 - 1);
    }
    if (j1 < NBIN) {
        hscan[j1] = ex + c0;
        h[j1] = ex + c0;
        int b1 = c1 ? atomicAdd(&cursor[j1], c1) : 0;
        hoff[j1] = j1 * BCAP1 + clampi(b1, BCAP1 - 1);
    }
    __syncthreads();
    for (int i = 0; i < ne; ++i) {
        int r = clampi(rr[i], NN - 1);
        int c = clampi(cc[i], NN - 1);
        int bin = r >> 7;
        int p = atomicAdd(&h[bin], 1);       // LDS cursor, block-private
        p = clampi(p, n - 1);                // hardening
        sKey[p] = ((unsigned)r << 16) | (unsigned)c;
        sAW[p] = aw2[i];
    }
    __syncthreads();
    for (int p = tid; p < n; p += 256) {
        unsigned key = sKey[p];
        int bin = (int)(key >> 23);          // = row >> 7
        int d = clampi(hoff[bin] + (p - hscan[bin]), LENE - 1);
        e1[d] = make_uint2(key, sAW[p]);     // single 8B interleaved write
    }
}

// Pass 2 (hist-free, r30): one block per 128-row bin. Row counts come from
// pass1's global rowcnt -> LDS scan -> placement loop reads the e1 window
// ONCE (was twice) and places via per-row LDS cursors. Emits row_desc[r] =
// start|(niters<<24); pads each row to multiple-of-8 kv slots with kv=0.
__global__ __launch_bounds__(256) void pass2_kernel(
        const uint2* __restrict__ e1, const int* __restrict__ cursor,
        const int* __restrict__ rowcnt,
        unsigned* __restrict__ kvA2, unsigned* __restrict__ kvW2,
        unsigned* __restrict__ row_desc) {
    __shared__ int rh[128];
    __shared__ int rs[128];
    __shared__ int cur[128];
    int bin = blockIdx.x, tid = threadIdx.x;
    int r0 = bin << 7;
    int rows = NN - r0; if (rows > 128) rows = 128;
    int ebase = bin * BCAP1;
    int size = clampi(cursor[bin], CAP2);    // bin fill (cap: hardening)
    int pbase = bin * BCAP;

    if (tid < 128) rh[tid] = (tid < rows) ? clampi(rowcnt[r0 + tid], 2040) : 0;
    __syncthreads();
    int cnt  = (tid < 128) ? rh[tid] : 0;
    int plen = (cnt + 7) & ~7;
    if (tid < 128) rs[tid] = plen;
    __syncthreads();
    for (int off = 1; off < 128; off <<= 1) {
        int t = (tid >= off && tid < 128) ? rs[tid - off] : 0;
        __syncthreads();
        if (tid < 128) rs[tid] += t;
        __syncthreads();
    }
    int rofs = (tid < 128) ? clampi(rs[tid] - plen, BCAP - 8) : 0;
    if (tid < 128) cur[tid] = rofs;
    if (tid < rows)
        row_desc[r0 + tid] = (unsigned)(pbase + rofs) | ((unsigned)(plen >> 3) << 24);
    __syncthreads();
    for (int i = tid; i < size; i += 256) {
        uint2 e = e1[ebase + i];             // single window read (L2/L3)
        unsigned key = e.x;
        unsigned aw  = e.y;
        int rl = (key >> 16) & 127;
        int p = atomicAdd(&cur[rl], 1);
        p = clampi(p, BCAP - 1);             // hardening
        unsigned c = key & 0xFFFFu;
        kvA2[pbase + p] = (aw & 0xFFFF0000u) | c;
        kvW2[pbase + p] = (aw << 16) | c;
    }
    __syncthreads();
    if (tid < rows) {
        int cnt2 = rh[tid];
        int pl = (cnt2 + 7) & ~7;
        for (int q = cnt2; q < pl; ++q) {
            int d = clampi(rofs + q, BCAP - 1);
            kvA2[pbase + d] = 0u;
            kvW2[pbase + d] = 0u;
        }
    }
}

// 16 lanes per row; lane l owns batch pair (2l, 2l+1) as one fp16x2 dword.
// 4 rows per wave64 (r15/r20 structure: uniform counted loop over rows
// padded to multiple-of-8 edges, uint2 kv loads, depth-1 kv prefetch, fp32
// accumulation, packed dword store).
// FINAL=1 (last A-pass): writes fp32 out[b*NN+r] = result * 2^24 directly
// (fused transpose_out; skips the intermediate fp16 rounding).
template <int WITH_BIAS, int FINAL>
__global__ __launch_bounds__(256) void spmm_kernel(
        const uint2* __restrict__ kv2, const unsigned* __restrict__ row_desc,
        const unsigned* __restrict__ in32, unsigned* __restrict__ out32,
        const float* __restrict__ bias, float outScale, float biasScale,
        float* __restrict__ outf) {
    int t = blockIdx.x * 256 + threadIdx.x;
    int r = t >> 4;                          // one row per 16 lanes
    int l = t & 15;                          // batch-pair index
    if (r >= NN) return;
    unsigned d = row_desc[r];
    int niter = (int)(d >> 24);
    int base2 = clampi((int)(d & 0xFFFFFFu), LENP - 8) >> 1;  // 8-slot aligned
    float accL = 0.0f, accH = 0.0f;          // batch 2l, 2l+1
    uint2 k2[4];
    if (niter > 0) {
#pragma unroll
        for (int q = 0; q < 4; ++q) k2[q] = kv2[base2 + q];
    }
    for (int it = 0; it < niter; ++it) {
        unsigned k[8];
#pragma unroll
        for (int q = 0; q < 4; ++q) { k[2 * q] = k2[q].x; k[2 * q + 1] = k2[q].y; }
        unsigned gd[8];
#pragma unroll
        for (int j = 0; j < 8; ++j) gd[j] = in32[((k[j] & 0xFFFFu) << 4) + l];
        if (it + 1 < niter) {
            int nb2 = base2 + (it + 1) * 4;
#pragma unroll
            for (int q = 0; q < 4; ++q) k2[q] = kv2[nb2 + q];
        }
#pragma unroll
        for (int j = 0; j < 8; ++j) {
            float v = kv_val(k[j]);
            union { unsigned u; _Float16 h[2]; } cv;
            cv.u = gd[j];
            accL += v * (float)cv.h[0];
            accH += v * (float)cv.h[1];
        }
    }
    float rL = accL * outScale, rH = accH * outScale;
    if (WITH_BIAS) {
        float bb = bias[r] * biasScale;
        rL += bb; rH += bb;
    }
    if (FINAL) {
        // fused transpose_out: undo cumulative 256^-3 state scaling (x 2^24)
        outf[(2 * l) * NN + r]     = rL * 16777216.0f;
        outf[(2 * l + 1) * NN + r] = rH * 16777216.0f;
    } else {
        union { unsigned u; _Float16 h[2]; } o;
        o.h[0] = (_Float16)rL;
        o.h[1] = (_Float16)rH;
        out32[(r << 4) + l] = o.u;
    }
}

extern "C" void kernel_launch(void* const* d_in, const int* in_sizes, int n_in,
                              void* d_out, int out_size, void* d_ws, size_t ws_size,
                              hipStream_t stream) {
    const float* x        = (const float*)d_in[0];
    const float* adj_vals = (const float*)d_in[1];
    const float* w_vals   = (const float*)d_in[2];
    const float* bias     = (const float*)d_in[3];
    const int*   row      = (const int*)d_in[4];
    const int*   col      = (const int*)d_in[5];
    float* out = (float*)d_out;

    // Workspace (~45 MB of the 256 MiB ws)
    uint2*     e1        = (uint2*)d_ws;             // LENE windowed {key, aw}
    unsigned*  kvA2      = (unsigned*)(e1 + LENE);   // LENP padded kv (A)
    unsigned*  kvW2      = kvA2 + LENP;              // LENP padded kv (W)
    _Float16*  xt16      = (_Float16*)(kvW2 + LENP); // NB fp16
    _Float16*  tmp16     = xt16 + NB;                // NB fp16
    int*       cursor    = (int*)(tmp16 + NB);       // NBIN bin-fill cursors
    int*       rowcnt    = cursor + NBIN;            // NNP per-row counts
    unsigned*  row_desc  = (unsigned*)(rowcnt + NNP);  // NN

    const int BS = 256;
    const int grid_spmm = (NN * 16 + BS - 1) / BS;   // 3125

    // ---- single-pass bin grouping (cursor-claimed fixed windows) ----
    hipMemsetAsync(cursor, 0, (NBIN + NNP) * sizeof(int), stream);
    pass1_kernel<<<TIN_BLKS + NBLK1, BS, 0, stream>>>(row, col, adj_vals, w_vals,
                                                      cursor, rowcnt, e1, x, xt16);
    pass2_kernel<<<NBIN, BS, 0, stream>>>(e1, cursor, rowcnt, kvA2, kvW2, row_desc);

    const uint2* kvA = (const uint2*)kvA2;
    const uint2* kvW = (const uint2*)kvW2;
    const unsigned* xt32  = (const unsigned*)xt16;
    unsigned*       xt32w = (unsigned*)xt16;
    const unsigned* tm32  = (const unsigned*)tmp16;
    unsigned*       tm32w = (unsigned*)tmp16;

    // ---- dense passes (scaled fp16 state: state_l = xt_l * 256^-l) ----
    const float r256 = 1.0f / 256.0f;
    spmm_kernel<0, 0><<<grid_spmm, BS, 0, stream>>>(kvW, row_desc, xt32, tm32w,
                                                    nullptr, 1.0f, 0.0f, nullptr);
    spmm_kernel<1, 0><<<grid_spmm, BS, 0, stream>>>(kvA, row_desc, tm32, xt32w,
                                                    bias, r256, 1.0f / 256.0f, nullptr);
    spmm_kernel<0, 0><<<grid_spmm, BS, 0, stream>>>(kvW, row_desc, xt32, tm32w,
                                                    nullptr, 1.0f, 0.0f, nullptr);
    spmm_kernel<1, 0><<<grid_spmm, BS, 0, stream>>>(kvA, row_desc, tm32, xt32w,
                                                    bias, r256, 1.0f / 65536.0f, nullptr);
    spmm_kernel<0, 0><<<grid_spmm, BS, 0, stream>>>(kvW, row_desc, xt32, tm32w,
                                                    nullptr, 1.0f, 0.0f, nullptr);
    spmm_kernel<1, 1><<<grid_spmm, BS, 0, stream>>>(kvA, row_desc, tm32, xt32w,
                                                    bias, r256, 1.0f / 16777216.0f, out);
}

// Round 16
// 230.229 us; speedup vs baseline: 1.2444x; 1.2444x over previous
//
#include <hip/hip_runtime.h>

// AdultConnectomeNetwork: 3 layers of xt = A_sp @ (W_sp @ xt) + bias.
// Round 31: EXACT revert to r26 (best measured: 233.0us). r27-r30 explored
// de-staged pass1, claim-window decoupling, cursor line-padding, and
// hist-offload-to-global-atomics - all neutral or regressive (r30: per-row
// device atomics cost +50MB fabric writes, pass1 100us). Established
// invariants: pass1 ~47us across 5 structural variants (serial floor),
// spmm ~60us across 3 variants (L2 transaction floor), fixed overhead
// ~50-60us. This is the converged configuration:
//  - pass1: staged LDS bin sort (CHUNK=3072, 391 128-row bins), vectorized
//    int4/float4 edge loads held in registers, wave-shuffle scan, global
//    cursor-claimed bin windows, interleaved uint2 {key,aw} burst writes,
//    LDS-tiled coalesced input transpose fused as trailing blocks.
//  - pass2: de-staged (no sKey/sAW LDS): hist loop + L2-hot re-read.
//  - spmm: 16 lanes/row fp16x2, uint2 kv, depth-1 prefetch, fp32 accum,
//    scaled fp16 state (256^-l), fused final fp32 transpose-out.
// Hardening: computed indices clamped (logic error -> absmax fail, not fault).

#define NN 50000
#define NNZ_E 1600000
#define NB (NN * 32)
#define CHUNK 3072
#define NBLK1 ((NNZ_E + CHUNK - 1) / CHUNK)      // 521
#define NBIN ((NN + 127) / 128)                  // 391 bins of 128 rows
#define CAP2 5120                                // bin fill cap (mean 4092, +16 sigma)
#define BCAP1 6144                               // e1 window slots per bin
#define LENE (NBIN * BCAP1)                      // 2402304 e1 slots (19.2 MB)
#define BCAP 6144                                // padded kv capacity per bin
#define LENP (NBIN * BCAP)                       // 2402304 padded kv slots
#define TIN_BLKS 196                             // transpose tiles of 256 n

__device__ __forceinline__ int clampi(int v, int hi) {  // [0, hi]
    v = v < 0 ? 0 : v;
    return v > hi ? hi : v;
}

__device__ __forceinline__ unsigned short f2h(float v) {
    union { _Float16 h; unsigned short u; } cv;
    cv.h = (_Float16)v;
    return cv.u;
}

__device__ __forceinline__ float kv_val(unsigned kv) {
    union { unsigned short u; _Float16 h; } cv;
    cv.u = (unsigned short)(kv >> 16);
    return (float)cv.h;
}

// Pass 1: per-chunk in-LDS bin sort; block claims its segment of each bin's
// fixed window via one global atomicAdd per nonempty bin; payload emitted as
// interleaved uint2 {key, aw}. key = (row<<16)|col. Blocks >= NBLK1 run the
// LDS-tiled coalesced input transpose (fp32 [B,N] -> fp16 [N,32]).
__global__ __launch_bounds__(256) void pass1_kernel(
        const int* __restrict__ row, const int* __restrict__ col,
        const float* __restrict__ a, const float* __restrict__ w,
        int* __restrict__ cursor, uint2* __restrict__ e1,
        const float* __restrict__ x, _Float16* __restrict__ xt) {
    __shared__ int h[NBIN];                  // counts -> staging cursors
    __shared__ int hscan[NBIN];              // block-local exclusive scan
    __shared__ int hoff[NBIN];               // claimed e1 index per bin
    __shared__ int wsum[4];
    __shared__ unsigned sBuf[2 * CHUNK];     // 24 KB: sKey | sAW, or transpose tile
    int blk = blockIdx.x, tid = threadIdx.x;

    if (blk >= NBLK1) {                      // ---- fused coalesced transpose ----
        _Float16* tl = (_Float16*)sBuf;      // [256][33] fp16 tile (16.9 KB)
        int n0 = (blk - NBLK1) * 256;
        int n = n0 + tid;
#pragma unroll 8
        for (int b = 0; b < 32; ++b) {       // coalesced x reads (1KB/wave rows)
            float v = (n < NN) ? x[b * NN + n] : 0.0f;
            tl[tid * 33 + b] = (_Float16)v;
        }
        __syncthreads();
#pragma unroll
        for (int k = 0; k < 4; ++k) {        // coalesced uint4 stores (16B/lane)
            int o = (tid + 256 * k) * 8;     // output offset within tile
            int nl = o >> 5;
            int b0 = o & 31;
            int nn = n0 + nl;
            if (nn < NN) {
                union { uint4 u4; _Float16 hh[8]; } pk;
#pragma unroll
                for (int j = 0; j < 8; ++j) pk.hh[j] = tl[nl * 33 + b0 + j];
                *(uint4*)&xt[nn * 32 + b0] = pk.u4;
            }
        }
        return;
    }

    int base = blk * CHUNK;
    int n = NNZ_E - base; if (n > CHUNK) n = CHUNK;   // 3072 or 2560 (both %4==0)
    int nv = n >> 2;
    unsigned* sKey = sBuf;
    unsigned* sAW  = sBuf + CHUNK;

    for (int j = tid; j < NBIN; j += 256) h[j] = 0;
    __syncthreads();

    // vectorized edge loads; edges stay in registers through staging
    int rr[12], cc[12];
    unsigned aw2[12];
    int ne = 0;
    const int4*   rv4 = (const int4*)row;
    const int4*   cv4 = (const int4*)col;
    const float4* av4 = (const float4*)a;
    const float4* wv4 = (const float4*)w;
    int b4 = base >> 2;
    for (int t4 = tid; t4 < nv; t4 += 256) {
        int4 r = rv4[b4 + t4];
        int4 c = cv4[b4 + t4];
        float4 af = av4[b4 + t4];
        float4 wf = wv4[b4 + t4];
        rr[ne] = r.x; cc[ne] = c.x; aw2[ne] = ((unsigned)f2h(af.x) << 16) | f2h(wf.x); ++ne;
        rr[ne] = r.y; cc[ne] = c.y; aw2[ne] = ((unsigned)f2h(af.y) << 16) | f2h(wf.y); ++ne;
        rr[ne] = r.z; cc[ne] = c.z; aw2[ne] = ((unsigned)f2h(af.z) << 16) | f2h(wf.z); ++ne;
        rr[ne] = r.w; cc[ne] = c.w; aw2[ne] = ((unsigned)f2h(af.w) << 16) | f2h(wf.w); ++ne;
    }
    for (int i = 0; i < ne; ++i)
        atomicAdd(&h[clampi(rr[i], NN - 1) >> 7], 1);
    __syncthreads();

    // exclusive prefix over per-thread (c0+c1) via wave shuffle (2 barriers)
    int j0 = tid * 2, j1 = tid * 2 + 1;
    int c0 = (j0 < NBIN) ? h[j0] : 0;
    int c1 = (j1 < NBIN) ? h[j1] : 0;
    int tsum = c0 + c1;
    int lane = tid & 63, wid = tid >> 6;
    int inc = tsum;
#pragma unroll
    for (int off = 1; off < 64; off <<= 1) {
        int u = __shfl_up(inc, off, 64);
        if (lane >= off) inc += u;
    }
    if (lane == 63) wsum[wid] = inc;
    __syncthreads();                         // also orders h[] reads vs writes below
    int wo = 0;
#pragma unroll
    for (int q = 0; q < 4; ++q) if (q < wid) wo += wsum[q];
    int ex = wo + inc - tsum;

    // claim global window segments (one atomic per nonempty bin)
    if (j0 < NBIN) {
        hscan[j0] = ex;
        h[j0] = ex;
        int b0 = c0 ? atomicAdd(&cursor[j0], c0) : 0;
        hoff[j0] = j0 * BCAP1 + clampi(b0, BCAP1 - 1);
    }
    if (j1 < NBIN) {
        hscan[j1] = ex + c0;
        h[j1] = ex + c0;
        int b1 = c1 ? atomicAdd(&cursor[j1], c1) : 0;
        hoff[j1] = j1 * BCAP1 + clampi(b1, BCAP1 - 1);
    }
    __syncthreads();
    for (int i = 0; i < ne; ++i) {
        int r = clampi(rr[i], NN - 1);
        int c = clampi(cc[i], NN - 1);
        int bin = r >> 7;
        int p = atomicAdd(&h[bin], 1);       // LDS cursor, block-private
        p = clampi(p, n - 1);                // hardening
        sKey[p] = ((unsigned)r << 16) | (unsigned)c;
        sAW[p] = aw2[i];
    }
    __syncthreads();
    for (int p = tid; p < n; p += 256) {
        unsigned key = sKey[p];
        int bin = (int)(key >> 23);          // = row >> 7
        int d = clampi(hoff[bin] + (p - hscan[bin]), LENE - 1);
        e1[d] = make_uint2(key, sAW[p]);     // single 8B interleaved write
    }
}

// Pass 2: one block per 128-row bin (size from cursor[bin]); no LDS staging:
// loop 1 reads e1 window to histogram rows, loop 2 re-reads (L2-hot) and
// places via per-row LDS cursors. Emits row_desc[r] = start|(niters<<24);
// pads each row to multiple-of-8 kv slots with kv=0.
__global__ __launch_bounds__(256) void pass2_kernel(
        const uint2* __restrict__ e1, const int* __restrict__ cursor,
        unsigned* __restrict__ kvA2, unsigned* __restrict__ kvW2,
        unsigned* __restrict__ row_desc) {
    __shared__ int rh[128];
    __shared__ int rs[128];
    __shared__ int cur[128];
    int bin = blockIdx.x, tid = threadIdx.x;
    int r0 = bin << 7;
    int rows = NN - r0; if (rows > 128) rows = 128;
    int ebase = bin * BCAP1;
    int size = clampi(cursor[bin], CAP2);    // bin fill (cap: hardening)
    int pbase = bin * BCAP;

    if (tid < 128) rh[tid] = 0;
    __syncthreads();
    for (int i = tid; i < size; i += 256)
        atomicAdd(&rh[(e1[ebase + i].x >> 16) & 127], 1);
    __syncthreads();
    int cnt  = (tid < 128) ? rh[tid] : 0;
    int plen = (cnt + 7) & ~7;
    if (tid < 128) rs[tid] = plen;
    __syncthreads();
    for (int off = 1; off < 128; off <<= 1) {
        int t = (tid >= off && tid < 128) ? rs[tid - off] : 0;
        __syncthreads();
        if (tid < 128) rs[tid] += t;
        __syncthreads();
    }
    int rofs = (tid < 128) ? clampi(rs[tid] - plen, BCAP - 8) : 0;
    if (tid < 128) cur[tid] = rofs;
    if (tid < rows)
        row_desc[r0 + tid] = (unsigned)(pbase + rofs) | ((unsigned)(plen >> 3) << 24);
    __syncthreads();
    for (int i = tid; i < size; i += 256) {
        uint2 e = e1[ebase + i];             // L2-hot re-read (8B coalesced)
        unsigned key = e.x;
        unsigned aw  = e.y;
        int rl = (key >> 16) & 127;
        int p = atomicAdd(&cur[rl], 1);
        p = clampi(p, BCAP - 1);             // hardening
        unsigned c = key & 0xFFFFu;
        kvA2[pbase + p] = (aw & 0xFFFF0000u) | c;
        kvW2[pbase + p] = (aw << 16) | c;
    }
    __syncthreads();
    if (tid < rows) {
        int pl = (rh[tid] + 7) & ~7;
        for (int q = rh[tid]; q < pl; ++q) {
            int d = clampi(rofs + q, BCAP - 1);
            kvA2[pbase + d] = 0u;
            kvW2[pbase + d] = 0u;
        }
    }
}

// 16 lanes per row; lane l owns batch pair (2l, 2l+1) as one fp16x2 dword.
// 4 rows per wave64 (r15/r20 structure: uniform counted loop over rows
// padded to multiple-of-8 edges, uint2 kv loads, depth-1 kv prefetch, fp32
// accumulation, packed dword store).
// FINAL=1 (last A-pass): writes fp32 out[b*NN+r] = result * 2^24 directly
// (fused transpose_out; skips the intermediate fp16 rounding).
template <int WITH_BIAS, int FINAL>
__global__ __launch_bounds__(256) void spmm_kernel(
        const uint2* __restrict__ kv2, const unsigned* __restrict__ row_desc,
        const unsigned* __restrict__ in32, unsigned* __restrict__ out32,
        const float* __restrict__ bias, float outScale, float biasScale,
        float* __restrict__ outf) {
    int t = blockIdx.x * 256 + threadIdx.x;
    int r = t >> 4;                          // one row per 16 lanes
    int l = t & 15;                          // batch-pair index
    if (r >= NN) return;
    unsigned d = row_desc[r];
    int niter = (int)(d >> 24);
    int base2 = clampi((int)(d & 0xFFFFFFu), LENP - 8) >> 1;  // 8-slot aligned
    float accL = 0.0f, accH = 0.0f;          // batch 2l, 2l+1
    uint2 k2[4];
    if (niter > 0) {
#pragma unroll
        for (int q = 0; q < 4; ++q) k2[q] = kv2[base2 + q];
    }
    for (int it = 0; it < niter; ++it) {
        unsigned k[8];
#pragma unroll
        for (int q = 0; q < 4; ++q) { k[2 * q] = k2[q].x; k[2 * q + 1] = k2[q].y; }
        unsigned gd[8];
#pragma unroll
        for (int j = 0; j < 8; ++j) gd[j] = in32[((k[j] & 0xFFFFu) << 4) + l];
        if (it + 1 < niter) {
            int nb2 = base2 + (it + 1) * 4;
#pragma unroll
            for (int q = 0; q < 4; ++q) k2[q] = kv2[nb2 + q];
        }
#pragma unroll
        for (int j = 0; j < 8; ++j) {
            float v = kv_val(k[j]);
            union { unsigned u; _Float16 h[2]; } cv;
            cv.u = gd[j];
            accL += v * (float)cv.h[0];
            accH += v * (float)cv.h[1];
        }
    }
    float rL = accL * outScale, rH = accH * outScale;
    if (WITH_BIAS) {
        float bb = bias[r] * biasScale;
        rL += bb; rH += bb;
    }
    if (FINAL) {
        // fused transpose_out: undo cumulative 256^-3 state scaling (x 2^24)
        outf[(2 * l) * NN + r]     = rL * 16777216.0f;
        outf[(2 * l + 1) * NN + r] = rH * 16777216.0f;
    } else {
        union { unsigned u; _Float16 h[2]; } o;
        o.h[0] = (_Float16)rL;
        o.h[1] = (_Float16)rH;
        out32[(r << 4) + l] = o.u;
    }
}

extern "C" void kernel_launch(void* const* d_in, const int* in_sizes, int n_in,
                              void* d_out, int out_size, void* d_ws, size_t ws_size,
                              hipStream_t stream) {
    const float* x        = (const float*)d_in[0];
    const float* adj_vals = (const float*)d_in[1];
    const float* w_vals   = (const float*)d_in[2];
    const float* bias     = (const float*)d_in[3];
    const int*   row      = (const int*)d_in[4];
    const int*   col      = (const int*)d_in[5];
    float* out = (float*)d_out;

    // Workspace (~45 MB of the 256 MiB ws)
    uint2*     e1        = (uint2*)d_ws;             // LENE windowed {key, aw}
    unsigned*  kvA2      = (unsigned*)(e1 + LENE);   // LENP padded kv (A)
    unsigned*  kvW2      = kvA2 + LENP;              // LENP padded kv (W)
    _Float16*  xt16      = (_Float16*)(kvW2 + LENP); // NB fp16
    _Float16*  tmp16     = xt16 + NB;                // NB fp16
    int*       cursor    = (int*)(tmp16 + NB);       // NBIN bin-fill cursors
    unsigned*  row_desc  = (unsigned*)(cursor + NBIN + 8);  // NN

    const int BS = 256;
    const int grid_spmm = (NN * 16 + BS - 1) / BS;   // 3125

    // ---- single-pass bin grouping (cursor-claimed fixed windows) ----
    hipMemsetAsync(cursor, 0, NBIN * sizeof(int), stream);
    pass1_kernel<<<NBLK1 + TIN_BLKS, BS, 0, stream>>>(row, col, adj_vals, w_vals,
                                                      cursor, e1, x, xt16);
    pass2_kernel<<<NBIN, BS, 0, stream>>>(e1, cursor, kvA2, kvW2, row_desc);

    const uint2* kvA = (const uint2*)kvA2;
    const uint2* kvW = (const uint2*)kvW2;
    const unsigned* xt32  = (const unsigned*)xt16;
    unsigned*       xt32w = (unsigned*)xt16;
    const unsigned* tm32  = (const unsigned*)tmp16;
    unsigned*       tm32w = (unsigned*)tmp16;

    // ---- dense passes (scaled fp16 state: state_l = xt_l * 256^-l) ----
    const float r256 = 1.0f / 256.0f;
    spmm_kernel<0, 0><<<grid_spmm, BS, 0, stream>>>(kvW, row_desc, xt32, tm32w,
                                                    nullptr, 1.0f, 0.0f, nullptr);
    spmm_kernel<1, 0><<<grid_spmm, BS, 0, stream>>>(kvA, row_desc, tm32, xt32w,
                                                    bias, r256, 1.0f / 256.0f, nullptr);
    spmm_kernel<0, 0><<<grid_spmm, BS, 0, stream>>>(kvW, row_desc, xt32, tm32w,
                                                    nullptr, 1.0f, 0.0f, nullptr);
    spmm_kernel<1, 0><<<grid_spmm, BS, 0, stream>>>(kvA, row_desc, tm32, xt32w,
                                                    bias, r256, 1.0f / 65536.0f, nullptr);
    spmm_kernel<0, 0><<<grid_spmm, BS, 0, stream>>>(kvW, row_desc, xt32, tm32w,
                                                    nullptr, 1.0f, 0.0f, nullptr);
    spmm_kernel<1, 1><<<grid_spmm, BS, 0, stream>>>(kvA, row_desc, tm32, xt32w,
                                                    bias, r256, 1.0f / 16777216.0f, out);
}